// Round 6
// baseline (259.310 us; speedup 1.0000x reference)
//
#include <hip/hip_runtime.h>

// Problem: Embedding_6940667150787
//   idx:      [131072] int32 in [0, 198)
//   wordlist: [198, 512] float32
//   out:      [131072, 512] float32 = wordlist[idx] + positional_encoding
//
// PE: for j in 0..254: angle = i / 10000^(2j/512);
//     pe[i, 2j] = sin(angle), pe[i, 2j+1] = cos(angle); cols 510,511 = 0.
//
// R8: fill-shaped execution (low occupancy, long contiguous write streams).
//   Evidence: four structurally different kernels (R=4/32, global/LDS gather,
//   pure-store loop) all ~93-97us = 2.8 TB/s writes; fillBufferAligned does
//   6.6 TB/s at ~10% occupancy. Common factor in ours: 8192+ waves each
//   writing short 64KB-strided bursts -> DRAM row-buffer thrash. The fill:
//   ~1k waves, each streaming contiguously -> row hits.
//   This version: 256 blocks x 256 thr = 1024 waves; each WAVE owns 128
//   consecutive rows and writes its 256KB region strictly sequentially
//   (lane l covers float4-cols l and l+64; rows ascend). 4 sin/cos pairs
//   per lane, advanced by rotation recurrence (128 steps, err ~1e-5).
//   Gather = global loads from L2-resident wordlist (proven harmless);
//   idx staged in LDS (2KB).

#define L_TOTAL 131072
#define ROWS_PER_BLOCK 512
#define ROWS_PER_WAVE 128
#define CHUNK 4           // rows per inner batch (load-ahead depth)

typedef float f32x4 __attribute__((ext_vector_type(4)));

__device__ __forceinline__ void sincos_fast(float a, float& s, float& c) {
    // Cody-Waite reduction by 2*pi (FMA), then HW transcendental
    // (input in REVOLUTIONS).
    const float INV2PI = 0.15915493667125702f;
    const float PI2_HI = 6.2831854820251465f;
    const float PI2_LO = -1.7484555314695172e-7f;
    float k = rintf(a * INV2PI);               // exact in fp32 (k <= ~2.1e4)
    float r = fmaf(-k, PI2_HI, a);
    r = fmaf(-k, PI2_LO, r);                   // |r| <= pi, err ~4e-7 rad
    float rev = r * INV2PI;
    s = __builtin_amdgcn_sinf(rev);            // v_sin_f32: sin(rev*2pi)
    c = __builtin_amdgcn_cosf(rev);            // v_cos_f32
}

__global__ __launch_bounds__(256) void embed_pe_kernel(
    const int* __restrict__ idx,
    const float* __restrict__ wordlist,
    float* __restrict__ out)
{
    __shared__ int idx_lds[ROWS_PER_BLOCK];    // 2 KB

    int tid     = threadIdx.x;
    int bid     = blockIdx.x;
    int rowbase = bid * ROWS_PER_BLOCK;

    // Stage this block's idx slice (two coalesced 1KB loads).
    for (int u = tid; u < ROWS_PER_BLOCK; u += 256)
        idx_lds[u] = idx[rowbase + u];
    __syncthreads();

    int wave  = tid >> 6;
    int lane  = tid & 63;
    int wrow0 = wave * ROWS_PER_WAVE;          // block-local first row
    int i0    = rowbase + wrow0;               // global first row of wave

    // Lane l covers float4-cols l and l+64 of each row:
    //   pairs j0=2l, j1=2l+1 (floats 4l..4l+3) and
    //   pairs j2=2l+128, j3=2l+129 (floats 256+4l..256+4l+3).
    const float K = 0.051905126483205076f;     // log2(10000) / 256
    float invf0 = exp2f(-(float)(2 * lane)       * K);
    float invf1 = exp2f(-(float)(2 * lane + 1)   * K);
    float invf2 = exp2f(-(float)(2 * lane + 128) * K);
    float invf3 = exp2f(-(float)(2 * lane + 129) * K);

    float s0, c0, s1, c1, s2, c2, s3, c3;
    float sd0, cd0, sd1, cd1, sd2, cd2, sd3, cd3;
    sincos_fast((float)i0 * invf0, s0, c0);
    sincos_fast((float)i0 * invf1, s1, c1);
    sincos_fast((float)i0 * invf2, s2, c2);
    sincos_fast((float)i0 * invf3, s3, c3);
    sincos_fast(invf0, sd0, cd0);
    sincos_fast(invf1, sd1, cd1);
    sincos_fast(invf2, sd2, cd2);
    sincos_fast(invf3, sd3, cd3);

    // Pair j=255 (lane 63, second half) -> cols 510,511 must be 0.
    // (0,0) is a fixed point of the rotation recurrence.
    if (lane == 63) { s3 = 0.0f; c3 = 0.0f; }

    const f32x4* wl = (const f32x4*)wordlist;
    f32x4*       op = (f32x4*)out + (size_t)i0 * 128 + lane;

    for (int ch = 0; ch < ROWS_PER_WAVE / CHUNK; ++ch) {
        // Tokens for this batch (uniform per wave; ds_read broadcast).
        int toks[CHUNK];
#pragma unroll
        for (int k = 0; k < CHUNK; ++k)
            toks[k] = idx_lds[wrow0 + ch * CHUNK + k];

        // Issue all gather loads up front (L2-resident wordlist).
        f32x4 wa[CHUNK], wb[CHUNK];
#pragma unroll
        for (int k = 0; k < CHUNK; ++k) {
            const f32x4* p = wl + (size_t)toks[k] * 128 + lane;
            wa[k] = p[0];
            wb[k] = p[64];
        }

        // Compute + store: wave writes 2KB rows strictly sequentially.
#pragma unroll
        for (int k = 0; k < CHUNK; ++k) {
            int r = ch * CHUNK + k;
            f32x4 o0, o1;
            o0[0] = wa[k][0] + s0;
            o0[1] = wa[k][1] + c0;
            o0[2] = wa[k][2] + s1;
            o0[3] = wa[k][3] + c1;
            o1[0] = wb[k][0] + s2;
            o1[1] = wb[k][1] + c2;
            o1[2] = wb[k][2] + s3;
            o1[3] = wb[k][3] + c3;
            op[(size_t)r * 128]      = o0;
            op[(size_t)r * 128 + 64] = o1;

            // rotate all 4 pairs forward by one row: (s,c) <- angle + invf
            float t;
            t  = fmaf(s0, cd0, c0 * sd0);
            c0 = fmaf(c0, cd0, -s0 * sd0); s0 = t;
            t  = fmaf(s1, cd1, c1 * sd1);
            c1 = fmaf(c1, cd1, -s1 * sd1); s1 = t;
            t  = fmaf(s2, cd2, c2 * sd2);
            c2 = fmaf(c2, cd2, -s2 * sd2); s2 = t;
            t  = fmaf(s3, cd3, c3 * sd3);
            c3 = fmaf(c3, cd3, -s3 * sd3); s3 = t;
        }
    }
}

extern "C" void kernel_launch(void* const* d_in, const int* in_sizes, int n_in,
                              void* d_out, int out_size, void* d_ws, size_t ws_size,
                              hipStream_t stream) {
    const int*   idx      = (const int*)d_in[0];
    const float* wordlist = (const float*)d_in[1];
    float*       out      = (float*)d_out;

    int grid = L_TOTAL / ROWS_PER_BLOCK;       // 256 blocks, ~1 per CU
    embed_pe_kernel<<<grid, 256, 0, stream>>>(idx, wordlist, out);
}